// Round 6
// baseline (1337.267 us; speedup 1.0000x reference)
//
#include <hip/hip_runtime.h>
#include <hip/hip_bf16.h>
#include <math.h>

// ---------------------------------------------------------------------------
// LSTM_55327768708454:  T=128 B=256 D=512 H=1024 O=1
// Round 15: consolidation. persist = EXACT r11 (TC=32, aggregator barrier,
//   3-deep A prefetch, setprio) - the measured best (177us/dispatch); r12-r14
//   barrier variants all regressed. Non-persist tail shrunk with safe moves:
//   (1) cvt + first-layer GEMM batched upfront (one M=32768 launch),
//   (2) XCD-aware block swizzle in gemm_bt (nwg%8==0 -> bijective; adjacent
//       same-XCD blocks share B-panels in L2),
//   (3) unchanged out_head/copy. Goal: modest win + surface gemm2's real
//   per-dispatch time in top-5 to decide on an 8-phase port next round.
// ---------------------------------------------------------------------------

#define T_STEPS 128
#define BATCH   256
#define DIM     512
#define HID     1024
#define GATES   4096
#define FPAD    32   // ints per flag slot (128B)

typedef __attribute__((ext_vector_type(8))) short short8;
typedef __attribute__((ext_vector_type(4))) float f4;
typedef __attribute__((ext_vector_type(4))) int i4;

__device__ __forceinline__ short f2bf(float f) {
    union { float f; unsigned u; } x; x.f = f;
    unsigned r = (x.u + 0x7fffu + ((x.u >> 16) & 1u)) >> 16;
    return (short)r;
}
__device__ __forceinline__ float bf2f(short s) {
    union { unsigned u; float f; } x; x.u = ((unsigned)(unsigned short)s) << 16;
    return x.f;
}
__device__ __forceinline__ float sigm(float x) { return 1.f / (1.f + __expf(-x)); }
__device__ __forceinline__ float tanh_fast(float x) { return 2.f / (1.f + __expf(-2.f * x)) - 1.f; }

__device__ __forceinline__ void gll16(const void* g, void* l) {
    __builtin_amdgcn_global_load_lds(
        (const __attribute__((address_space(1))) void*)g,
        (__attribute__((address_space(3))) void*)l, 16, 0, 0);
}
__device__ __forceinline__ void store16_wt(void* p, i4 v) {
    asm volatile("global_store_dwordx4 %0, %1, off sc0 sc1"
                 :: "v"(p), "v"(v) : "memory");
}

// ---------------- helpers ----------------
__global__ __launch_bounds__(256) void cvt_f32_bf16(const float* __restrict__ in,
                                                    short* __restrict__ out, int n4) {
    int i = blockIdx.x * 256 + threadIdx.x;
    if (i < n4) {
        float4 v = ((const float4*)in)[i];
        union { short s[4]; long long ll; } r;
        r.s[0] = f2bf(v.x); r.s[1] = f2bf(v.y); r.s[2] = f2bf(v.z); r.s[3] = f2bf(v.w);
        ((long long*)out)[i] = r.ll;
    }
}

// h0 fp32 (B,H) -> blocked bf16 [slice][b][8]
__global__ __launch_bounds__(256) void cvt_h0_blocked(const float* __restrict__ h0,
                                                      short* __restrict__ dst) {
    int b = blockIdx.x, k0 = threadIdx.x * 4;
    float4 v = *(const float4*)&h0[(size_t)b * HID + k0];
    union { short s[4]; long long ll; } p;
    p.s[0] = f2bf(v.x); p.s[1] = f2bf(v.y); p.s[2] = f2bf(v.z); p.s[3] = f2bf(v.w);
    *(long long*)&dst[(k0 >> 3) * (BATCH * 8) + b * 8 + (k0 & 7)] = p.ll;
}

// out row r' = hc*4+g  <-  in row g*1024+hc  (W_ih: xg cols gate-packed)
__global__ __launch_bounds__(256) void cvt_permute_rows(const float* __restrict__ in,
                                                        short* __restrict__ out) {
    int r = blockIdx.x;
    int hc = r >> 2, g = r & 3;
    const float* src = in + (size_t)(g * HID + hc) * HID;
    short* dst = out + (size_t)r * HID;
    int c = threadIdx.x * 4;
    float4 v = *(const float4*)&src[c];
    union { short s[4]; long long ll; } p;
    p.s[0] = f2bf(v.x); p.s[1] = f2bf(v.y); p.s[2] = f2bf(v.z); p.s[3] = f2bf(v.w);
    *(long long*)&dst[c] = p.ll;
}

__global__ __launch_bounds__(256) void bias_sum_perm(const float* __restrict__ a,
                                                     const float* __restrict__ b,
                                                     float* __restrict__ o) {
    int r = blockIdx.x * 256 + threadIdx.x;
    int hc = r >> 2, g = r & 3;
    int src = g * HID + hc;
    o[r] = a[src] + b[src];
}

__global__ __launch_bounds__(256) void copy_f32v4(const float* __restrict__ in,
                                                  float* __restrict__ out, int n4) {
    int i = blockIdx.x * 256 + threadIdx.x;
    if (i < n4) ((float4*)out)[i] = ((const float4*)in)[i];
}

__global__ __launch_bounds__(256) void zero_i32(int* __restrict__ p, int n) {
    for (int i = blockIdx.x * 256 + threadIdx.x; i < n; i += gridDim.x * 256)
        p[i] = 0;
}

// ---------------- m97-style bf16 GEMM:  C = A @ B^T + bias, opt relu ----------------
// XCD-aware tile swizzle: requires gridDim.x*gridDim.y % 8 == 0 (both launches
// use nwg=2048). Same-XCD-consecutive tiles walk M within one N-band -> shared
// B-panel in that XCD's L2.
__global__ __launch_bounds__(256) void gemm_bt(const short* __restrict__ A,
                                               const short* __restrict__ B,
                                               const float* __restrict__ bias,
                                               short* __restrict__ C,
                                               int M, int N, int K, int do_relu) {
    __shared__ __align__(16) short As[128 * 32];
    __shared__ __align__(16) short Bs[128 * 32];
    const int tid = threadIdx.x, wave = tid >> 6, lane = tid & 63;
    const int wm = (wave >> 1) * 64, wn = (wave & 1) * 64;

    const int flat = blockIdx.y * gridDim.x + blockIdx.x;
    const int cpx = (gridDim.x * gridDim.y) >> 3;
    const int swz = (flat & 7) * cpx + (flat >> 3);
    const int bm = (swz % gridDim.x) * 128, bn = (swz / gridDim.x) * 128;

    const int sr = lane >> 2, sc = (lane & 3) * 8;

    f4 acc[4][4] = {};

    for (int k0 = 0; k0 < K; k0 += 32) {
        __syncthreads();
#pragma unroll
        for (int j = 0; j < 2; ++j) {
            int c = wave * 2 + j;
            gll16(&A[(size_t)(bm + c * 16 + sr) * K + k0 + sc], &As[c * 512]);
            gll16(&B[(size_t)(bn + c * 16 + sr) * K + k0 + sc], &Bs[c * 512]);
        }
        __syncthreads();
        short8 af[4], bfr[4];
#pragma unroll
        for (int i = 0; i < 4; ++i) {
            af[i]  = *(const short8*)&As[(wm + i * 16 + (lane & 15)) * 32 + (lane >> 4) * 8];
            bfr[i] = *(const short8*)&Bs[(wn + i * 16 + (lane & 15)) * 32 + (lane >> 4) * 8];
        }
#pragma unroll
        for (int i = 0; i < 4; ++i)
#pragma unroll
            for (int j = 0; j < 4; ++j)
                acc[i][j] = __builtin_amdgcn_mfma_f32_16x16x32_bf16(af[i], bfr[j], acc[i][j], 0, 0, 0);
    }

    const int lc = lane & 15, lr = (lane >> 4) * 4;
#pragma unroll
    for (int i = 0; i < 4; ++i) {
#pragma unroll
        for (int j = 0; j < 4; ++j) {
            int col = bn + wn + j * 16 + lc;
            float bv = bias[col];
#pragma unroll
            for (int r = 0; r < 4; ++r) {
                int row = bm + wm + i * 16 + lr + r;
                float v = acc[i][j][r] + bv;
                if (do_relu) v = fmaxf(v, 0.f);
                C[(size_t)row * N + col] = f2bf(v);
            }
        }
    }
}

// ---------------- persistent recurrence over TC steps (EXACT r11) ----------------
// 512 blocks (2/CU): bg = bx>>7 (64 batch rows), cg = bx&127 (8 h-cols).
// hist slots are BLOCKED: [slice(=k/8)][b][8], slice cg owned by block (.,cg).
// K-loop: A-loads pipelined 3 groups deep (24 x 16B in flight) to cover IC
// latency; MFMA clusters wrapped in s_setprio. Aggregator barrier (r7).
__global__ __launch_bounds__(256) void lstm_persist(const short* __restrict__ Whh,
                                                    const short* __restrict__ xgc,
                                                    short* __restrict__ hist,
                                                    float* __restrict__ cf,
                                                    float* __restrict__ hT,
                                                    float* __restrict__ cT,
                                                    int* __restrict__ flags,
                                                    int* __restrict__ go,
                                                    int TC, int last) {
    __shared__ __align__(16) short Bf[32768];   // 64 KB W_hh strip fragments
    __shared__ __align__(16) short Ht[512];     // 1 KB h-tile staging (64 rows x 8 cols)
    const int tid = threadIdx.x, w = tid >> 6, lane = tid & 63;
    const int bg = blockIdx.x >> 7, cg = blockIdx.x & 127;
    const int bb = bg * 64, hc0 = cg * 8;
    const int hcl = lane & 7, gp = (lane >> 3) & 1, q = lane >> 4;

    // ---- fill W_hh strip fragments once ----
#pragma unroll
    for (int i = 0; i < 16; ++i) {
        int p = w * 16 + i;
        int c = p >> 1, t = p & 1;
        gll16(&Whh[(size_t)((t * 2 + gp) * HID + hc0 + hcl) * HID + c * 32 + q * 8],
              &Bf[p * 512]);
    }

    // ---- c-state into registers ----
    const int rowb = bb + w * 16 + q * 4 + gp * 2;       // rows rowb, rowb+1
    float creg[2];
#pragma unroll
    for (int e = 0; e < 2; ++e)
        creg[e] = cf[(size_t)(rowb + e) * HID + hc0 + hcl];

    __syncthreads();   // strip ready

    // prime xg for step 0
    unsigned long long xw[2], xwn[2];
#pragma unroll
    for (int e = 0; e < 2; ++e)
        xw[e] = *(const unsigned long long*)&xgc[(size_t)(rowb + e) * GATES
                                                 + (hc0 + hcl) * 4];

#define ISSUE_A(buf, g)                                                        \
    _Pragma("unroll")                                                          \
    for (int i = 0; i < 8; ++i)                                                \
        buf[i] = *(const short8*)(abase + (size_t)((g) * 8 + i) * astr);

#define COMPUTE_A(buf, g)                                                      \
    __builtin_amdgcn_s_setprio(1);                                             \
    _Pragma("unroll")                                                          \
    for (int i = 0; i < 8; ++i) {                                              \
        short8 b0 = *(const short8*)&Bf[(((g) * 8 + i) * 2 + 0) * 512 + lane * 8]; \
        short8 b1 = *(const short8*)&Bf[(((g) * 8 + i) * 2 + 1) * 512 + lane * 8]; \
        acc0 = __builtin_amdgcn_mfma_f32_16x16x32_bf16(buf[i], b0, acc0, 0, 0, 0); \
        acc1 = __builtin_amdgcn_mfma_f32_16x16x32_bf16(buf[i], b1, acc1, 0, 0, 0); \
    }                                                                          \
    __builtin_amdgcn_s_setprio(0);

    for (int tt = 0; tt < TC; ++tt) {
        // ---- prefetch next step's xg ----
        if (tt + 1 < TC) {
#pragma unroll
            for (int e = 0; e < 2; ++e)
                xwn[e] = *(const unsigned long long*)&xgc[(size_t)((tt + 1) * BATCH + rowb + e) * GATES
                                                          + (hc0 + hcl) * 4];
        }

        // ---- K-loop: A from blocked hist (slice = c*4+q), B resident in LDS,
        //      3-group-deep explicit A prefetch pipeline ----
        const short* abase = hist + (size_t)tt * BATCH * HID
                           + (size_t)q * (BATCH * 8) + (size_t)(bb + w * 16 + (lane & 15)) * 8;
        const size_t astr = (size_t)4 * (BATCH * 8);
        f4 acc0 = {}, acc1 = {};
        short8 ab0[8], ab1[8], ab2[8];
        ISSUE_A(ab0, 0)
        ISSUE_A(ab1, 1)
        ISSUE_A(ab2, 2)
        COMPUTE_A(ab0, 0)
        ISSUE_A(ab0, 3)
        COMPUTE_A(ab1, 1)
        COMPUTE_A(ab2, 2)
        COMPUTE_A(ab0, 3)

        // ---- gate exchange across lane^8 ----
        float p0[4], p1[4];
#pragma unroll
        for (int r = 0; r < 4; ++r) {
            p0[r] = __shfl_xor(acc0[r], 8);
            p1[r] = __shfl_xor(acc1[r], 8);
        }

        int glast = last && (tt == TC - 1);
#pragma unroll
        for (int e = 0; e < 2; ++e) {
            int r = gp * 2 + e;
            size_t b = rowb + e;
            float gi = gp ? p0[r] : acc0[r];
            float gf = gp ? acc0[r] : p0[r];
            float gg = gp ? p1[r] : acc1[r];
            float go_ = gp ? acc1[r] : p1[r];
            gi += bf2f((short)(xw[e] & 0xffff));
            gf += bf2f((short)((xw[e] >> 16) & 0xffff));
            gg += bf2f((short)((xw[e] >> 32) & 0xffff));
            go_ += bf2f((short)((xw[e] >> 48) & 0xffff));
            float si = sigm(gi), sf = sigm(gf), tg = tanh_fast(gg), so = sigm(go_);
            float cn = sf * creg[e] + si * tg;
            float hv = so * tanh_fast(cn);
            creg[e] = cn;
            Ht[(w * 16 + q * 4 + gp * 2 + e) * 8 + hcl] = f2bf(hv);
            if (glast) {
                hT[b * HID + hc0 + hcl] = hv;
                cT[b * HID + hc0 + hcl] = cn;
            }
        }
        xw[0] = xwn[0]; xw[1] = xwn[1];
        __syncthreads();   // Ht complete

        // ---- packed h stores: 64 x 16B CONTIGUOUS (8 full lines, single writer) ----
        short* hn = hist + (size_t)(tt + 1) * BATCH * HID
                  + (size_t)cg * (BATCH * 8) + (size_t)bb * 8;
        if (tid < 64)
            store16_wt(&hn[tid * 8], *(const i4*)&Ht[tid * 8]);

        // ---- aggregator barrier (r7 topology, lowest congestion) ----
        if (tt < TC - 1) {
            __syncthreads();   // drains vmcnt for the 64 storing threads
            const int base = (tt * 4 + bg) * 128 * FPAD;
            if (tid == 0)
                __hip_atomic_store(&flags[base + cg * FPAD], 1,
                                   __ATOMIC_RELAXED, __HIP_MEMORY_SCOPE_AGENT);
            if (cg == 0) {
                if (tid < 128) {
                    while (__hip_atomic_load(&flags[base + tid * FPAD],
                                             __ATOMIC_RELAXED, __HIP_MEMORY_SCOPE_AGENT) == 0)
                        __builtin_amdgcn_s_sleep(1);
                }
                __syncthreads();
                if (tid == 0)
                    __hip_atomic_store(&go[(tt * 4 + bg) * FPAD], 1,
                                       __ATOMIC_RELAXED, __HIP_MEMORY_SCOPE_AGENT);
            } else {
                if (tid == 0) {
                    while (__hip_atomic_load(&go[(tt * 4 + bg) * FPAD],
                                             __ATOMIC_RELAXED, __HIP_MEMORY_SCOPE_AGENT) == 0)
                        __builtin_amdgcn_s_sleep(1);
                }
                __syncthreads();
            }
        }
    }

#undef ISSUE_A
#undef COMPUTE_A

    // ---- write back c-state for next chunk ----
#pragma unroll
    for (int e = 0; e < 2; ++e)
        cf[(size_t)(rowb + e) * HID + hc0 + hcl] = creg[e];
}

// ---------------- output head over one chunk of h history (blocked layout) ----------------
__global__ __launch_bounds__(256) void out_head(const short* __restrict__ hs,
                                                const float* __restrict__ Wout,
                                                const float* __restrict__ bout,
                                                float* __restrict__ out) {
    int row = blockIdx.x * 4 + (threadIdx.x >> 6);   // tt*256 + b
    int lane = threadIdx.x & 63;
    int tt = row >> 8, b = row & 255;
    const short* sb = hs + (size_t)(tt + 1) * BATCH * HID + b * 8;   // slot tt+1
    const float2* w2 = (const float2*)Wout;
    float s = 0.f;
#pragma unroll
    for (int j = 0; j < 8; ++j) {
        int m = j * 64 + lane;                       // pair index 0..511, k=2m
        int pk = *(const int*)&sb[(size_t)(m >> 2) * (BATCH * 8) + 2 * (m & 3)];
        float2 wv = w2[m];
        union { unsigned u; float f; } lo, hi;
        lo.u = ((unsigned)pk) << 16;
        hi.u = ((unsigned)pk) & 0xffff0000u;
        s += lo.f * wv.x + hi.f * wv.y;
    }
#pragma unroll
    for (int off = 32; off; off >>= 1) s += __shfl_down(s, off);
    if (lane == 0) out[row] = s + bout[0];
}

// ---------------------------------------------------------------------------
extern "C" void kernel_launch(void* const* d_in, const int* in_sizes, int n_in,
                              void* d_out, int out_size, void* d_ws, size_t ws_size,
                              hipStream_t stream) {
    const float* inputs = (const float*)d_in[0];
    const float* h0     = (const float*)d_in[1];
    const float* c0     = (const float*)d_in[2];
    const float* W1     = (const float*)d_in[3];
    const float* b1     = (const float*)d_in[4];
    const float* W_ih   = (const float*)d_in[5];
    const float* W_hh   = (const float*)d_in[6];
    const float* b_ih   = (const float*)d_in[7];
    const float* b_hh   = (const float*)d_in[8];
    const float* W_out  = (const float*)d_in[9];
    const float* b_out  = (const float*)d_in[10];

    float* out = (float*)d_out;
    float* hT  = out + (size_t)T_STEPS * BATCH;
    float* cT  = hT + (size_t)BATCH * HID;

    char* base = (char*)d_ws;
    size_t off = 0;
    auto alloc = [&](size_t bytes) -> char* {
        char* q = base + off;
        off += (bytes + 255) & ~(size_t)255;
        return q;
    };
    short* W1b   = (short*)alloc((size_t)HID * DIM * 2);
    short* Wihb  = (short*)alloc((size_t)GATES * HID * 2);      // row-permuted
    short* Whhb  = (short*)alloc((size_t)GATES * HID * 2);      // plain layout
    float* biasf = (float*)alloc((size_t)GATES * 4);            // permuted
    float* cf    = (float*)alloc((size_t)BATCH * HID * 4);
    int*   flags = (int*)alloc((size_t)T_STEPS * 4 * 128 * FPAD * 4);  // 8 MB
    int*   go    = (int*)alloc((size_t)T_STEPS * 4 * FPAD * 4);        // 64 KB

    // upfront full-sequence buffers (ws proven >= ~275 MB by r14's TC=64 run)
    short* inb_a = (short*)alloc((size_t)T_STEPS * BATCH * DIM * 2);   // 33.5 MB
    short* xb_a  = (short*)alloc((size_t)T_STEPS * BATCH * HID * 2);   // 67 MB

    size_t per_t = (size_t)BATCH * GATES * 2 + (size_t)BATCH * HID * 2;
    int TC = 32;
    while (TC > 1 && off + (size_t)TC * per_t + (size_t)BATCH * HID * 2 + 65536 > ws_size)
        TC >>= 1;

    short* hhist = (short*)alloc((size_t)(TC + 1) * BATCH * HID * 2);
    short* xgb_c = (short*)alloc((size_t)TC * BATCH * GATES * 2);

    // ---- weight prep + flag zero (flags indexed by absolute t -> zero once) ----
    cvt_f32_bf16<<<(HID * DIM / 4 + 255) / 256, 256, 0, stream>>>(W1, W1b, HID * DIM / 4);
    cvt_permute_rows<<<GATES, 256, 0, stream>>>(W_ih, Wihb);
    cvt_f32_bf16<<<(GATES * HID / 4 + 255) / 256, 256, 0, stream>>>(W_hh, Whhb, GATES * HID / 4);
    bias_sum_perm<<<GATES / 256, 256, 0, stream>>>(b_ih, b_hh, biasf);
    cvt_h0_blocked<<<BATCH, 256, 0, stream>>>(h0, hhist);
    copy_f32v4<<<(BATCH * HID / 4 + 255) / 256, 256, 0, stream>>>(c0, cf, BATCH * HID / 4);
    zero_i32<<<512, 256, 0, stream>>>(flags, T_STEPS * 4 * 128 * FPAD + T_STEPS * 4 * FPAD);

    // ---- upfront: convert ALL inputs, first-layer GEMM for ALL timesteps ----
    {
        int Ma = T_STEPS * BATCH;                       // 32768
        cvt_f32_bf16<<<(Ma * DIM / 4 + 255) / 256, 256, 0, stream>>>(
            inputs, inb_a, Ma * DIM / 4);
        gemm_bt<<<dim3(Ma / 128, HID / 128), 256, 0, stream>>>(
            inb_a, W1b, b1, xb_a, Ma, HID, DIM, 1);     // grid 256x8 = 2048 (%8==0)
    }

    // ---- chunked pipeline ----
    for (int t0 = 0; t0 < T_STEPS; t0 += TC) {
        int Mc = TC * BATCH;
        int last = (t0 + TC >= T_STEPS);
        gemm_bt<<<dim3(Mc / 128, GATES / 128), 256, 0, stream>>>(
            xb_a + (size_t)t0 * BATCH * HID, Wihb, biasf, xgb_c,
            Mc, GATES, HID, 0);                          // grid 64x32 = 2048 (%8==0)

        lstm_persist<<<512, 256, 0, stream>>>(Whhb, xgb_c, hhist, cf, hT, cT,
                                              flags + (size_t)t0 * 4 * 128 * FPAD,
                                              go + (size_t)t0 * 4 * FPAD,
                                              TC, last);

        out_head<<<TC * BATCH / 4, 256, 0, stream>>>(hhist, W_out, b_out,
                                                     out + (size_t)t0 * BATCH);
        copy_f32v4<<<(BATCH * HID * 2 / 16 + 255) / 256, 256, 0, stream>>>(
            (const float*)(hhist + (size_t)TC * BATCH * HID), (float*)hhist,
            BATCH * HID * 2 / 16);
    }
}

// Round 8
// 1320.953 us; speedup vs baseline: 1.0124x; 1.0124x over previous
//
#include <hip/hip_runtime.h>
#include <hip/hip_bf16.h>
#include <math.h>

// ---------------------------------------------------------------------------
// LSTM_55327768708454:  T=128 B=256 D=512 H=1024 O=1
// Round 17: r16 with the staging bug fixed. gemm_bt2 staged only rows 0..63
//   (2 u-iters x 8 rows/call); BK=64 rows are 128B so each gll16 covers 8
//   rows -> need 4 u-iters (r0 = wave*32 + u*8) for the full 128-row tile.
//   Rows 64..127 were uninitialized LDS -> NaN. Swizzle + dbuf logic verified
//   by algebra (lds[r][s]=glob[r][s^(r&7)], read t^(r&7); barrier protects
//   buffer cur^1 across iterations). persist = EXACT r11; rest = r15.
// ---------------------------------------------------------------------------

#define T_STEPS 128
#define BATCH   256
#define DIM     512
#define HID     1024
#define GATES   4096
#define FPAD    32   // ints per flag slot (128B)

typedef __attribute__((ext_vector_type(8))) short short8;
typedef __attribute__((ext_vector_type(4))) float f4;
typedef __attribute__((ext_vector_type(4))) int i4;

__device__ __forceinline__ short f2bf(float f) {
    union { float f; unsigned u; } x; x.f = f;
    unsigned r = (x.u + 0x7fffu + ((x.u >> 16) & 1u)) >> 16;
    return (short)r;
}
__device__ __forceinline__ float bf2f(short s) {
    union { unsigned u; float f; } x; x.u = ((unsigned)(unsigned short)s) << 16;
    return x.f;
}
__device__ __forceinline__ float sigm(float x) { return 1.f / (1.f + __expf(-x)); }
__device__ __forceinline__ float tanh_fast(float x) { return 2.f / (1.f + __expf(-2.f * x)) - 1.f; }

__device__ __forceinline__ void gll16(const void* g, void* l) {
    __builtin_amdgcn_global_load_lds(
        (const __attribute__((address_space(1))) void*)g,
        (__attribute__((address_space(3))) void*)l, 16, 0, 0);
}
__device__ __forceinline__ void store16_wt(void* p, i4 v) {
    asm volatile("global_store_dwordx4 %0, %1, off sc0 sc1"
                 :: "v"(p), "v"(v) : "memory");
}

// ---------------- helpers ----------------
__global__ __launch_bounds__(256) void cvt_f32_bf16(const float* __restrict__ in,
                                                    short* __restrict__ out, int n4) {
    int i = blockIdx.x * 256 + threadIdx.x;
    if (i < n4) {
        float4 v = ((const float4*)in)[i];
        union { short s[4]; long long ll; } r;
        r.s[0] = f2bf(v.x); r.s[1] = f2bf(v.y); r.s[2] = f2bf(v.z); r.s[3] = f2bf(v.w);
        ((long long*)out)[i] = r.ll;
    }
}

// h0 fp32 (B,H) -> blocked bf16 [slice][b][8]
__global__ __launch_bounds__(256) void cvt_h0_blocked(const float* __restrict__ h0,
                                                      short* __restrict__ dst) {
    int b = blockIdx.x, k0 = threadIdx.x * 4;
    float4 v = *(const float4*)&h0[(size_t)b * HID + k0];
    union { short s[4]; long long ll; } p;
    p.s[0] = f2bf(v.x); p.s[1] = f2bf(v.y); p.s[2] = f2bf(v.z); p.s[3] = f2bf(v.w);
    *(long long*)&dst[(k0 >> 3) * (BATCH * 8) + b * 8 + (k0 & 7)] = p.ll;
}

// out row r' = hc*4+g  <-  in row g*1024+hc  (W_ih: xg cols gate-packed)
__global__ __launch_bounds__(256) void cvt_permute_rows(const float* __restrict__ in,
                                                        short* __restrict__ out) {
    int r = blockIdx.x;
    int hc = r >> 2, g = r & 3;
    const float* src = in + (size_t)(g * HID + hc) * HID;
    short* dst = out + (size_t)r * HID;
    int c = threadIdx.x * 4;
    float4 v = *(const float4*)&src[c];
    union { short s[4]; long long ll; } p;
    p.s[0] = f2bf(v.x); p.s[1] = f2bf(v.y); p.s[2] = f2bf(v.z); p.s[3] = f2bf(v.w);
    *(long long*)&dst[c] = p.ll;
}

__global__ __launch_bounds__(256) void bias_sum_perm(const float* __restrict__ a,
                                                     const float* __restrict__ b,
                                                     float* __restrict__ o) {
    int r = blockIdx.x * 256 + threadIdx.x;
    int hc = r >> 2, g = r & 3;
    int src = g * HID + hc;
    o[r] = a[src] + b[src];
}

__global__ __launch_bounds__(256) void copy_f32v4(const float* __restrict__ in,
                                                  float* __restrict__ out, int n4) {
    int i = blockIdx.x * 256 + threadIdx.x;
    if (i < n4) ((float4*)out)[i] = ((const float4*)in)[i];
}

__global__ __launch_bounds__(256) void zero_i32(int* __restrict__ p, int n) {
    for (int i = blockIdx.x * 256 + threadIdx.x; i < n; i += gridDim.x * 256)
        p[i] = 0;
}

// ---------------- gemm_bt2: 128^2 / BK=64 / dbuf / swizzled ----------------
// C = A @ B^T + bias, opt relu. A:(M,K) B:(N,K) row-major bf16, C bf16.
// Requires M%128==0, N%128==0, K%128==0, grid (M/128, N/128).
// LDS: As/Bs[buf][row][64]; 16B slot s of row r holds global slot s^(r&7).
__global__ __launch_bounds__(256) void gemm_bt2(const short* __restrict__ A,
                                                const short* __restrict__ B,
                                                const float* __restrict__ bias,
                                                short* __restrict__ C,
                                                int M, int N, int K, int do_relu) {
    __shared__ __align__(16) short As[2][128 * 64];   // 32 KB
    __shared__ __align__(16) short Bs[2][128 * 64];   // 32 KB
    const int tid = threadIdx.x, wave = tid >> 6, lane = tid & 63;
    const int wm = (wave >> 1) * 64, wn = (wave & 1) * 64;

    // XCD-aware bijective block swizzle (m204 form; exact when nwg%8==0)
    const int nwg = gridDim.x * gridDim.y;
    const int flat = blockIdx.y * gridDim.x + blockIdx.x;
    const int qq = nwg >> 3, rr = nwg & 7;
    const int xcd = flat & 7, oin = flat >> 3;
    const int swz = (xcd < rr ? xcd * (qq + 1) : rr * (qq + 1) + (xcd - rr) * qq) + oin;
    const int bm = (swz % gridDim.x) * 128, bn = (swz / gridDim.x) * 128;

    // each gll16 stages 8 rows (64 lanes x 16B = 1024B; row = 128B).
    // 4 u-iters/wave x 4 waves = 16 calls -> full 128 rows per operand.
#define STAGE2(bufi, kt)                                                       \
    {                                                                          \
        const int k0_ = (kt) * 64;                                             \
        _Pragma("unroll")                                                      \
        for (int u = 0; u < 4; ++u) {                                          \
            int r0 = wave * 32 + u * 8;                                        \
            int row = r0 + (lane >> 3);                                        \
            int kof = ((lane & 7) ^ (row & 7)) * 8;                            \
            gll16(&A[(size_t)(bm + row) * K + k0_ + kof], &As[bufi][r0 * 64]); \
            gll16(&B[(size_t)(bn + row) * K + k0_ + kof], &Bs[bufi][r0 * 64]); \
        }                                                                      \
    }

    f4 acc[4][4] = {};
    const int NT = K >> 6;

    STAGE2(0, 0)
    __syncthreads();      // implicit vmcnt(0) drain before barrier

    int cur = 0;
    for (int kt = 0; kt < NT; ++kt) {
        // issue next tile's staging first (other buffer; protected by the
        // barrier at the end of the previous iteration)
        if (kt + 1 < NT) STAGE2(cur ^ 1, kt + 1)

#pragma unroll
        for (int ks = 0; ks < 2; ++ks) {
            short8 af[4], bfr[4];
#pragma unroll
            for (int i = 0; i < 4; ++i) {
                int ra = wm + i * 16 + (lane & 15);
                int sa = (ks * 4 + (lane >> 4)) ^ (ra & 7);
                af[i] = *(const short8*)&As[cur][ra * 64 + sa * 8];
                int rb = wn + i * 16 + (lane & 15);
                int sb = (ks * 4 + (lane >> 4)) ^ (rb & 7);
                bfr[i] = *(const short8*)&Bs[cur][rb * 64 + sb * 8];
            }
            __builtin_amdgcn_s_setprio(1);
#pragma unroll
            for (int i = 0; i < 4; ++i)
#pragma unroll
                for (int j = 0; j < 4; ++j)
                    acc[i][j] = __builtin_amdgcn_mfma_f32_16x16x32_bf16(af[i], bfr[j], acc[i][j], 0, 0, 0);
            __builtin_amdgcn_s_setprio(0);
        }
        __syncthreads();  // drains this wave's staging vmcnt + publishes buffer
        cur ^= 1;
    }
#undef STAGE2

    const int lc = lane & 15, lr = (lane >> 4) * 4;
#pragma unroll
    for (int i = 0; i < 4; ++i) {
#pragma unroll
        for (int j = 0; j < 4; ++j) {
            int col = bn + wn + j * 16 + lc;
            float bv = bias[col];
#pragma unroll
            for (int r = 0; r < 4; ++r) {
                int row = bm + wm + i * 16 + lr + r;
                float v = acc[i][j][r] + bv;
                if (do_relu) v = fmaxf(v, 0.f);
                C[(size_t)row * N + col] = f2bf(v);
            }
        }
    }
}

// ---------------- persistent recurrence over TC steps (EXACT r11) ----------------
// 512 blocks (2/CU): bg = bx>>7 (64 batch rows), cg = bx&127 (8 h-cols).
// hist slots are BLOCKED: [slice(=k/8)][b][8], slice cg owned by block (.,cg).
// K-loop: A-loads pipelined 3 groups deep; MFMA clusters in s_setprio.
// Aggregator barrier (r7 topology).
__global__ __launch_bounds__(256) void lstm_persist(const short* __restrict__ Whh,
                                                    const short* __restrict__ xgc,
                                                    short* __restrict__ hist,
                                                    float* __restrict__ cf,
                                                    float* __restrict__ hT,
                                                    float* __restrict__ cT,
                                                    int* __restrict__ flags,
                                                    int* __restrict__ go,
                                                    int TC, int last) {
    __shared__ __align__(16) short Bf[32768];   // 64 KB W_hh strip fragments
    __shared__ __align__(16) short Ht[512];     // 1 KB h-tile staging (64 rows x 8 cols)
    const int tid = threadIdx.x, w = tid >> 6, lane = tid & 63;
    const int bg = blockIdx.x >> 7, cg = blockIdx.x & 127;
    const int bb = bg * 64, hc0 = cg * 8;
    const int hcl = lane & 7, gp = (lane >> 3) & 1, q = lane >> 4;

    // ---- fill W_hh strip fragments once ----
#pragma unroll
    for (int i = 0; i < 16; ++i) {
        int p = w * 16 + i;
        int c = p >> 1, t = p & 1;
        gll16(&Whh[(size_t)((t * 2 + gp) * HID + hc0 + hcl) * HID + c * 32 + q * 8],
              &Bf[p * 512]);
    }

    // ---- c-state into registers ----
    const int rowb = bb + w * 16 + q * 4 + gp * 2;       // rows rowb, rowb+1
    float creg[2];
#pragma unroll
    for (int e = 0; e < 2; ++e)
        creg[e] = cf[(size_t)(rowb + e) * HID + hc0 + hcl];

    __syncthreads();   // strip ready

    // prime xg for step 0
    unsigned long long xw[2], xwn[2];
#pragma unroll
    for (int e = 0; e < 2; ++e)
        xw[e] = *(const unsigned long long*)&xgc[(size_t)(rowb + e) * GATES
                                                 + (hc0 + hcl) * 4];

#define ISSUE_A(buf, g)                                                        \
    _Pragma("unroll")                                                          \
    for (int i = 0; i < 8; ++i)                                                \
        buf[i] = *(const short8*)(abase + (size_t)((g) * 8 + i) * astr);

#define COMPUTE_A(buf, g)                                                      \
    __builtin_amdgcn_s_setprio(1);                                             \
    _Pragma("unroll")                                                          \
    for (int i = 0; i < 8; ++i) {                                              \
        short8 b0 = *(const short8*)&Bf[(((g) * 8 + i) * 2 + 0) * 512 + lane * 8]; \
        short8 b1 = *(const short8*)&Bf[(((g) * 8 + i) * 2 + 1) * 512 + lane * 8]; \
        acc0 = __builtin_amdgcn_mfma_f32_16x16x32_bf16(buf[i], b0, acc0, 0, 0, 0); \
        acc1 = __builtin_amdgcn_mfma_f32_16x16x32_bf16(buf[i], b1, acc1, 0, 0, 0); \
    }                                                                          \
    __builtin_amdgcn_s_setprio(0);

    for (int tt = 0; tt < TC; ++tt) {
        // ---- prefetch next step's xg ----
        if (tt + 1 < TC) {
#pragma unroll
            for (int e = 0; e < 2; ++e)
                xwn[e] = *(const unsigned long long*)&xgc[(size_t)((tt + 1) * BATCH + rowb + e) * GATES
                                                          + (hc0 + hcl) * 4];
        }

        // ---- K-loop: A from blocked hist (slice = c*4+q), B resident in LDS,
        //      3-group-deep explicit A prefetch pipeline ----
        const short* abase = hist + (size_t)tt * BATCH * HID
                           + (size_t)q * (BATCH * 8) + (size_t)(bb + w * 16 + (lane & 15)) * 8;
        const size_t astr = (size_t)4 * (BATCH * 8);
        f4 acc0 = {}, acc1 = {};
        short8 ab0[8], ab1[8], ab2[8];
        ISSUE_A(ab0, 0)
        ISSUE_A(ab1, 1)
        ISSUE_A(ab2, 2)
        COMPUTE_A(ab0, 0)
        ISSUE_A(ab0, 3)
        COMPUTE_A(ab1, 1)
        COMPUTE_A(ab2, 2)
        COMPUTE_A(ab0, 3)

        // ---- gate exchange across lane^8 ----
        float p0[4], p1[4];
#pragma unroll
        for (int r = 0; r < 4; ++r) {
            p0[r] = __shfl_xor(acc0[r], 8);
            p1[r] = __shfl_xor(acc1[r], 8);
        }

        int glast = last && (tt == TC - 1);
#pragma unroll
        for (int e = 0; e < 2; ++e) {
            int r = gp * 2 + e;
            size_t b = rowb + e;
            float gi = gp ? p0[r] : acc0[r];
            float gf = gp ? acc0[r] : p0[r];
            float gg = gp ? p1[r] : acc1[r];
            float go_ = gp ? acc1[r] : p1[r];
            gi += bf2f((short)(xw[e] & 0xffff));
            gf += bf2f((short)((xw[e] >> 16) & 0xffff));
            gg += bf2f((short)((xw[e] >> 32) & 0xffff));
            go_ += bf2f((short)((xw[e] >> 48) & 0xffff));
            float si = sigm(gi), sf = sigm(gf), tg = tanh_fast(gg), so = sigm(go_);
            float cn = sf * creg[e] + si * tg;
            float hv = so * tanh_fast(cn);
            creg[e] = cn;
            Ht[(w * 16 + q * 4 + gp * 2 + e) * 8 + hcl] = f2bf(hv);
            if (glast) {
                hT[b * HID + hc0 + hcl] = hv;
                cT[b * HID + hc0 + hcl] = cn;
            }
        }
        xw[0] = xwn[0]; xw[1] = xwn[1];
        __syncthreads();   // Ht complete

        // ---- packed h stores: 64 x 16B CONTIGUOUS (8 full lines, single writer) ----
        short* hn = hist + (size_t)(tt + 1) * BATCH * HID
                  + (size_t)cg * (BATCH * 8) + (size_t)bb * 8;
        if (tid < 64)
            store16_wt(&hn[tid * 8], *(const i4*)&Ht[tid * 8]);

        // ---- aggregator barrier (r7 topology, lowest congestion) ----
        if (tt < TC - 1) {
            __syncthreads();   // drains vmcnt for the 64 storing threads
            const int base = (tt * 4 + bg) * 128 * FPAD;
            if (tid == 0)
                __hip_atomic_store(&flags[base + cg * FPAD], 1,
                                   __ATOMIC_RELAXED, __HIP_MEMORY_SCOPE_AGENT);
            if (cg == 0) {
                if (tid < 128) {
                    while (__hip_atomic_load(&flags[base + tid * FPAD],
                                             __ATOMIC_RELAXED, __HIP_MEMORY_SCOPE_AGENT) == 0)
                        __builtin_amdgcn_s_sleep(1);
                }
                __syncthreads();
                if (tid == 0)
                    __hip_atomic_store(&go[(tt * 4 + bg) * FPAD], 1,
                                       __ATOMIC_RELAXED, __HIP_MEMORY_SCOPE_AGENT);
            } else {
                if (tid == 0) {
                    while (__hip_atomic_load(&go[(tt * 4 + bg) * FPAD],
                                             __ATOMIC_RELAXED, __HIP_MEMORY_SCOPE_AGENT) == 0)
                        __builtin_amdgcn_s_sleep(1);
                }
                __syncthreads();
            }
        }
    }

#undef ISSUE_A
#undef COMPUTE_A

    // ---- write back c-state for next chunk ----
#pragma unroll
    for (int e = 0; e < 2; ++e)
        cf[(size_t)(rowb + e) * HID + hc0 + hcl] = creg[e];
}

// ---------------- output head over one chunk of h history (blocked layout) ----------------
__global__ __launch_bounds__(256) void out_head(const short* __restrict__ hs,
                                                const float* __restrict__ Wout,
                                                const float* __restrict__ bout,
                                                float* __restrict__ out) {
    int row = blockIdx.x * 4 + (threadIdx.x >> 6);   // tt*256 + b
    int lane = threadIdx.x & 63;
    int tt = row >> 8, b = row & 255;
    const short* sb = hs + (size_t)(tt + 1) * BATCH * HID + b * 8;   // slot tt+1
    const float2* w2 = (const float2*)Wout;
    float s = 0.f;
#pragma unroll
    for (int j = 0; j < 8; ++j) {
        int m = j * 64 + lane;                       // pair index 0..511, k=2m
        int pk = *(const int*)&sb[(size_t)(m >> 2) * (BATCH * 8) + 2 * (m & 3)];
        float2 wv = w2[m];
        union { unsigned u; float f; } lo, hi;
        lo.u = ((unsigned)pk) << 16;
        hi.u = ((unsigned)pk) & 0xffff0000u;
        s += lo.f * wv.x + hi.f * wv.y;
    }
#pragma unroll
    for (int off = 32; off; off >>= 1) s += __shfl_down(s, off);
    if (lane == 0) out[row] = s + bout[0];
}

// ---------------------------------------------------------------------------
extern "C" void kernel_launch(void* const* d_in, const int* in_sizes, int n_in,
                              void* d_out, int out_size, void* d_ws, size_t ws_size,
                              hipStream_t stream) {
    const float* inputs = (const float*)d_in[0];
    const float* h0     = (const float*)d_in[1];
    const float* c0     = (const float*)d_in[2];
    const float* W1     = (const float*)d_in[3];
    const float* b1     = (const float*)d_in[4];
    const float* W_ih   = (const float*)d_in[5];
    const float* W_hh   = (const float*)d_in[6];
    const float* b_ih   = (const float*)d_in[7];
    const float* b_hh   = (const float*)d_in[8];
    const float* W_out  = (const float*)d_in[9];
    const float* b_out  = (const float*)d_in[10];

    float* out = (float*)d_out;
    float* hT  = out + (size_t)T_STEPS * BATCH;
    float* cT  = hT + (size_t)BATCH * HID;

    char* base = (char*)d_ws;
    size_t off = 0;
    auto alloc = [&](size_t bytes) -> char* {
        char* q = base + off;
        off += (bytes + 255) & ~(size_t)255;
        return q;
    };
    short* W1b   = (short*)alloc((size_t)HID * DIM * 2);
    short* Wihb  = (short*)alloc((size_t)GATES * HID * 2);      // row-permuted
    short* Whhb  = (short*)alloc((size_t)GATES * HID * 2);      // plain layout
    float* biasf = (float*)alloc((size_t)GATES * 4);            // permuted
    float* cf    = (float*)alloc((size_t)BATCH * HID * 4);
    int*   flags = (int*)alloc((size_t)T_STEPS * 4 * 128 * FPAD * 4);  // 8 MB
    int*   go    = (int*)alloc((size_t)T_STEPS * 4 * FPAD * 4);        // 64 KB

    // upfront full-sequence buffers
    short* inb_a = (short*)alloc((size_t)T_STEPS * BATCH * DIM * 2);   // 33.5 MB
    short* xb_a  = (short*)alloc((size_t)T_STEPS * BATCH * HID * 2);   // 67 MB

    size_t per_t = (size_t)BATCH * GATES * 2 + (size_t)BATCH * HID * 2;
    int TC = 32;
    while (TC > 1 && off + (size_t)TC * per_t + (size_t)BATCH * HID * 2 + 65536 > ws_size)
        TC >>= 1;

    short* hhist = (short*)alloc((size_t)(TC + 1) * BATCH * HID * 2);
    short* xgb_c = (short*)alloc((size_t)TC * BATCH * GATES * 2);

    // ---- weight prep + flag zero (flags indexed by absolute t -> zero once) ----
    cvt_f32_bf16<<<(HID * DIM / 4 + 255) / 256, 256, 0, stream>>>(W1, W1b, HID * DIM / 4);
    cvt_permute_rows<<<GATES, 256, 0, stream>>>(W_ih, Wihb);
    cvt_f32_bf16<<<(GATES * HID / 4 + 255) / 256, 256, 0, stream>>>(W_hh, Whhb, GATES * HID / 4);
    bias_sum_perm<<<GATES / 256, 256, 0, stream>>>(b_ih, b_hh, biasf);
    cvt_h0_blocked<<<BATCH, 256, 0, stream>>>(h0, hhist);
    copy_f32v4<<<(BATCH * HID / 4 + 255) / 256, 256, 0, stream>>>(c0, cf, BATCH * HID / 4);
    zero_i32<<<512, 256, 0, stream>>>(flags, T_STEPS * 4 * 128 * FPAD + T_STEPS * 4 * FPAD);

    // ---- upfront: convert ALL inputs, first-layer GEMM for ALL timesteps ----
    {
        int Ma = T_STEPS * BATCH;                       // 32768
        cvt_f32_bf16<<<(Ma * DIM / 4 + 255) / 256, 256, 0, stream>>>(
            inputs, inb_a, Ma * DIM / 4);
        gemm_bt2<<<dim3(Ma / 128, HID / 128), 256, 0, stream>>>(
            inb_a, W1b, b1, xb_a, Ma, HID, DIM, 1);     // grid 256x8 = 2048
    }

    // ---- chunked pipeline ----
    for (int t0 = 0; t0 < T_STEPS; t0 += TC) {
        int Mc = TC * BATCH;
        int last = (t0 + TC >= T_STEPS);
        gemm_bt2<<<dim3(Mc / 128, GATES / 128), 256, 0, stream>>>(
            xb_a + (size_t)t0 * BATCH * HID, Wihb, biasf, xgb_c,
            Mc, GATES, HID, 0);                          // grid 64x32 = 2048

        lstm_persist<<<512, 256, 0, stream>>>(Whhb, xgb_c, hhist, cf, hT, cT,
                                              flags + (size_t)t0 * 4 * 128 * FPAD,
                                              go + (size_t)t0 * 4 * FPAD,
                                              TC, last);

        out_head<<<TC * BATCH / 4, 256, 0, stream>>>(hhist, W_out, b_out,
                                                     out + (size_t)t0 * BATCH);
        copy_f32v4<<<(BATCH * HID * 2 / 16 + 255) / 256, 256, 0, stream>>>(
            (const float*)(hhist + (size_t)TC * BATCH * HID), (float*)hhist,
            BATCH * HID * 2 / 16);
    }
}

// Round 9
// 1276.165 us; speedup vs baseline: 1.0479x; 1.0351x over previous
//
#include <hip/hip_runtime.h>
#include <hip/hip_bf16.h>
#include <math.h>

// ---------------------------------------------------------------------------
// LSTM_55327768708454:  T=128 B=256 D=512 H=1024 O=1
// Round 18: plumbing consolidation + gemm2 measurement.
//   (1) hist_all: 129 h-history slots -> persist chains chunks in place
//       (hist = hhist + t0*B*H); inter-chunk copies removed; out_head runs
//       ONCE at the end over all 128 steps.
//   (2) ws-adaptive xg: if workspace fits, ALL xg computed in one M=32768
//       GEMM dispatch (lands in top-5 -> first direct gemm2 measurement);
//       else r17's chunked path. inb_a aliased into the xg region (dead
//       after gemm1) in both paths.
//   persist = EXACT r11 (frozen); gemm_bt2 = r17 (fixed staging).
// ---------------------------------------------------------------------------

#define T_STEPS 128
#define BATCH   256
#define DIM     512
#define HID     1024
#define GATES   4096
#define FPAD    32   // ints per flag slot (128B)

typedef __attribute__((ext_vector_type(8))) short short8;
typedef __attribute__((ext_vector_type(4))) float f4;
typedef __attribute__((ext_vector_type(4))) int i4;

__device__ __forceinline__ short f2bf(float f) {
    union { float f; unsigned u; } x; x.f = f;
    unsigned r = (x.u + 0x7fffu + ((x.u >> 16) & 1u)) >> 16;
    return (short)r;
}
__device__ __forceinline__ float bf2f(short s) {
    union { unsigned u; float f; } x; x.u = ((unsigned)(unsigned short)s) << 16;
    return x.f;
}
__device__ __forceinline__ float sigm(float x) { return 1.f / (1.f + __expf(-x)); }
__device__ __forceinline__ float tanh_fast(float x) { return 2.f / (1.f + __expf(-2.f * x)) - 1.f; }

__device__ __forceinline__ void gll16(const void* g, void* l) {
    __builtin_amdgcn_global_load_lds(
        (const __attribute__((address_space(1))) void*)g,
        (__attribute__((address_space(3))) void*)l, 16, 0, 0);
}
__device__ __forceinline__ void store16_wt(void* p, i4 v) {
    asm volatile("global_store_dwordx4 %0, %1, off sc0 sc1"
                 :: "v"(p), "v"(v) : "memory");
}

// ---------------- helpers ----------------
__global__ __launch_bounds__(256) void cvt_f32_bf16(const float* __restrict__ in,
                                                    short* __restrict__ out, int n4) {
    int i = blockIdx.x * 256 + threadIdx.x;
    if (i < n4) {
        float4 v = ((const float4*)in)[i];
        union { short s[4]; long long ll; } r;
        r.s[0] = f2bf(v.x); r.s[1] = f2bf(v.y); r.s[2] = f2bf(v.z); r.s[3] = f2bf(v.w);
        ((long long*)out)[i] = r.ll;
    }
}

// h0 fp32 (B,H) -> blocked bf16 [slice][b][8]
__global__ __launch_bounds__(256) void cvt_h0_blocked(const float* __restrict__ h0,
                                                      short* __restrict__ dst) {
    int b = blockIdx.x, k0 = threadIdx.x * 4;
    float4 v = *(const float4*)&h0[(size_t)b * HID + k0];
    union { short s[4]; long long ll; } p;
    p.s[0] = f2bf(v.x); p.s[1] = f2bf(v.y); p.s[2] = f2bf(v.z); p.s[3] = f2bf(v.w);
    *(long long*)&dst[(k0 >> 3) * (BATCH * 8) + b * 8 + (k0 & 7)] = p.ll;
}

// out row r' = hc*4+g  <-  in row g*1024+hc  (W_ih: xg cols gate-packed)
__global__ __launch_bounds__(256) void cvt_permute_rows(const float* __restrict__ in,
                                                        short* __restrict__ out) {
    int r = blockIdx.x;
    int hc = r >> 2, g = r & 3;
    const float* src = in + (size_t)(g * HID + hc) * HID;
    short* dst = out + (size_t)r * HID;
    int c = threadIdx.x * 4;
    float4 v = *(const float4*)&src[c];
    union { short s[4]; long long ll; } p;
    p.s[0] = f2bf(v.x); p.s[1] = f2bf(v.y); p.s[2] = f2bf(v.z); p.s[3] = f2bf(v.w);
    *(long long*)&dst[c] = p.ll;
}

__global__ __launch_bounds__(256) void bias_sum_perm(const float* __restrict__ a,
                                                     const float* __restrict__ b,
                                                     float* __restrict__ o) {
    int r = blockIdx.x * 256 + threadIdx.x;
    int hc = r >> 2, g = r & 3;
    int src = g * HID + hc;
    o[r] = a[src] + b[src];
}

__global__ __launch_bounds__(256) void copy_f32v4(const float* __restrict__ in,
                                                  float* __restrict__ out, int n4) {
    int i = blockIdx.x * 256 + threadIdx.x;
    if (i < n4) ((float4*)out)[i] = ((const float4*)in)[i];
}

__global__ __launch_bounds__(256) void zero_i32(int* __restrict__ p, int n) {
    for (int i = blockIdx.x * 256 + threadIdx.x; i < n; i += gridDim.x * 256)
        p[i] = 0;
}

// ---------------- gemm_bt2: 128^2 / BK=64 / dbuf / swizzled ----------------
// C = A @ B^T + bias, opt relu. A:(M,K) B:(N,K) row-major bf16, C bf16.
// Requires M%128==0, N%128==0, K%128==0, grid (M/128, N/128).
// LDS: As/Bs[buf][row][64]; 16B slot s of row r holds global slot s^(r&7).
__global__ __launch_bounds__(256) void gemm_bt2(const short* __restrict__ A,
                                                const short* __restrict__ B,
                                                const float* __restrict__ bias,
                                                short* __restrict__ C,
                                                int M, int N, int K, int do_relu) {
    __shared__ __align__(16) short As[2][128 * 64];   // 32 KB
    __shared__ __align__(16) short Bs[2][128 * 64];   // 32 KB
    const int tid = threadIdx.x, wave = tid >> 6, lane = tid & 63;
    const int wm = (wave >> 1) * 64, wn = (wave & 1) * 64;

    // XCD-aware bijective block swizzle (m204 form; exact when nwg%8==0)
    const int nwg = gridDim.x * gridDim.y;
    const int flat = blockIdx.y * gridDim.x + blockIdx.x;
    const int qq = nwg >> 3, rr = nwg & 7;
    const int xcd = flat & 7, oin = flat >> 3;
    const int swz = (xcd < rr ? xcd * (qq + 1) : rr * (qq + 1) + (xcd - rr) * qq) + oin;
    const int bm = (swz % gridDim.x) * 128, bn = (swz / gridDim.x) * 128;

    // each gll16 stages 8 rows (64 lanes x 16B = 1024B; row = 128B).
    // 4 u-iters/wave x 4 waves = 16 calls -> full 128 rows per operand.
#define STAGE2(bufi, kt)                                                       \
    {                                                                          \
        const int k0_ = (kt) * 64;                                             \
        _Pragma("unroll")                                                      \
        for (int u = 0; u < 4; ++u) {                                          \
            int r0 = wave * 32 + u * 8;                                        \
            int row = r0 + (lane >> 3);                                        \
            int kof = ((lane & 7) ^ (row & 7)) * 8;                            \
            gll16(&A[(size_t)(bm + row) * K + k0_ + kof], &As[bufi][r0 * 64]); \
            gll16(&B[(size_t)(bn + row) * K + k0_ + kof], &Bs[bufi][r0 * 64]); \
        }                                                                      \
    }

    f4 acc[4][4] = {};
    const int NT = K >> 6;

    STAGE2(0, 0)
    __syncthreads();      // implicit vmcnt(0) drain before barrier

    int cur = 0;
    for (int kt = 0; kt < NT; ++kt) {
        if (kt + 1 < NT) STAGE2(cur ^ 1, kt + 1)

#pragma unroll
        for (int ks = 0; ks < 2; ++ks) {
            short8 af[4], bfr[4];
#pragma unroll
            for (int i = 0; i < 4; ++i) {
                int ra = wm + i * 16 + (lane & 15);
                int sa = (ks * 4 + (lane >> 4)) ^ (ra & 7);
                af[i] = *(const short8*)&As[cur][ra * 64 + sa * 8];
                int rb = wn + i * 16 + (lane & 15);
                int sb = (ks * 4 + (lane >> 4)) ^ (rb & 7);
                bfr[i] = *(const short8*)&Bs[cur][rb * 64 + sb * 8];
            }
            __builtin_amdgcn_s_setprio(1);
#pragma unroll
            for (int i = 0; i < 4; ++i)
#pragma unroll
                for (int j = 0; j < 4; ++j)
                    acc[i][j] = __builtin_amdgcn_mfma_f32_16x16x32_bf16(af[i], bfr[j], acc[i][j], 0, 0, 0);
            __builtin_amdgcn_s_setprio(0);
        }
        __syncthreads();
        cur ^= 1;
    }
#undef STAGE2

    const int lc = lane & 15, lr = (lane >> 4) * 4;
#pragma unroll
    for (int i = 0; i < 4; ++i) {
#pragma unroll
        for (int j = 0; j < 4; ++j) {
            int col = bn + wn + j * 16 + lc;
            float bv = bias[col];
#pragma unroll
            for (int r = 0; r < 4; ++r) {
                int row = bm + wm + i * 16 + lr + r;
                float v = acc[i][j][r] + bv;
                if (do_relu) v = fmaxf(v, 0.f);
                C[(size_t)row * N + col] = f2bf(v);
            }
        }
    }
}

// ---------------- persistent recurrence over TC steps (EXACT r11) ----------------
// 512 blocks (2/CU): bg = bx>>7 (64 batch rows), cg = bx&127 (8 h-cols).
// hist slots are BLOCKED: [slice(=k/8)][b][8], slice cg owned by block (.,cg).
// K-loop: A-loads pipelined 3 groups deep; MFMA clusters in s_setprio.
// Aggregator barrier (r7 topology).
__global__ __launch_bounds__(256) void lstm_persist(const short* __restrict__ Whh,
                                                    const short* __restrict__ xgc,
                                                    short* __restrict__ hist,
                                                    float* __restrict__ cf,
                                                    float* __restrict__ hT,
                                                    float* __restrict__ cT,
                                                    int* __restrict__ flags,
                                                    int* __restrict__ go,
                                                    int TC, int last) {
    __shared__ __align__(16) short Bf[32768];   // 64 KB W_hh strip fragments
    __shared__ __align__(16) short Ht[512];     // 1 KB h-tile staging (64 rows x 8 cols)
    const int tid = threadIdx.x, w = tid >> 6, lane = tid & 63;
    const int bg = blockIdx.x >> 7, cg = blockIdx.x & 127;
    const int bb = bg * 64, hc0 = cg * 8;
    const int hcl = lane & 7, gp = (lane >> 3) & 1, q = lane >> 4;

    // ---- fill W_hh strip fragments once ----
#pragma unroll
    for (int i = 0; i < 16; ++i) {
        int p = w * 16 + i;
        int c = p >> 1, t = p & 1;
        gll16(&Whh[(size_t)((t * 2 + gp) * HID + hc0 + hcl) * HID + c * 32 + q * 8],
              &Bf[p * 512]);
    }

    // ---- c-state into registers ----
    const int rowb = bb + w * 16 + q * 4 + gp * 2;       // rows rowb, rowb+1
    float creg[2];
#pragma unroll
    for (int e = 0; e < 2; ++e)
        creg[e] = cf[(size_t)(rowb + e) * HID + hc0 + hcl];

    __syncthreads();   // strip ready

    // prime xg for step 0
    unsigned long long xw[2], xwn[2];
#pragma unroll
    for (int e = 0; e < 2; ++e)
        xw[e] = *(const unsigned long long*)&xgc[(size_t)(rowb + e) * GATES
                                                 + (hc0 + hcl) * 4];

#define ISSUE_A(buf, g)                                                        \
    _Pragma("unroll")                                                          \
    for (int i = 0; i < 8; ++i)                                                \
        buf[i] = *(const short8*)(abase + (size_t)((g) * 8 + i) * astr);

#define COMPUTE_A(buf, g)                                                      \
    __builtin_amdgcn_s_setprio(1);                                             \
    _Pragma("unroll")                                                          \
    for (int i = 0; i < 8; ++i) {                                              \
        short8 b0 = *(const short8*)&Bf[(((g) * 8 + i) * 2 + 0) * 512 + lane * 8]; \
        short8 b1 = *(const short8*)&Bf[(((g) * 8 + i) * 2 + 1) * 512 + lane * 8]; \
        acc0 = __builtin_amdgcn_mfma_f32_16x16x32_bf16(buf[i], b0, acc0, 0, 0, 0); \
        acc1 = __builtin_amdgcn_mfma_f32_16x16x32_bf16(buf[i], b1, acc1, 0, 0, 0); \
    }                                                                          \
    __builtin_amdgcn_s_setprio(0);

    for (int tt = 0; tt < TC; ++tt) {
        // ---- prefetch next step's xg ----
        if (tt + 1 < TC) {
#pragma unroll
            for (int e = 0; e < 2; ++e)
                xwn[e] = *(const unsigned long long*)&xgc[(size_t)((tt + 1) * BATCH + rowb + e) * GATES
                                                          + (hc0 + hcl) * 4];
        }

        // ---- K-loop: A from blocked hist (slice = c*4+q), B resident in LDS,
        //      3-group-deep explicit A prefetch pipeline ----
        const short* abase = hist + (size_t)tt * BATCH * HID
                           + (size_t)q * (BATCH * 8) + (size_t)(bb + w * 16 + (lane & 15)) * 8;
        const size_t astr = (size_t)4 * (BATCH * 8);
        f4 acc0 = {}, acc1 = {};
        short8 ab0[8], ab1[8], ab2[8];
        ISSUE_A(ab0, 0)
        ISSUE_A(ab1, 1)
        ISSUE_A(ab2, 2)
        COMPUTE_A(ab0, 0)
        ISSUE_A(ab0, 3)
        COMPUTE_A(ab1, 1)
        COMPUTE_A(ab2, 2)
        COMPUTE_A(ab0, 3)

        // ---- gate exchange across lane^8 ----
        float p0[4], p1[4];
#pragma unroll
        for (int r = 0; r < 4; ++r) {
            p0[r] = __shfl_xor(acc0[r], 8);
            p1[r] = __shfl_xor(acc1[r], 8);
        }

        int glast = last && (tt == TC - 1);
#pragma unroll
        for (int e = 0; e < 2; ++e) {
            int r = gp * 2 + e;
            size_t b = rowb + e;
            float gi = gp ? p0[r] : acc0[r];
            float gf = gp ? acc0[r] : p0[r];
            float gg = gp ? p1[r] : acc1[r];
            float go_ = gp ? acc1[r] : p1[r];
            gi += bf2f((short)(xw[e] & 0xffff));
            gf += bf2f((short)((xw[e] >> 16) & 0xffff));
            gg += bf2f((short)((xw[e] >> 32) & 0xffff));
            go_ += bf2f((short)((xw[e] >> 48) & 0xffff));
            float si = sigm(gi), sf = sigm(gf), tg = tanh_fast(gg), so = sigm(go_);
            float cn = sf * creg[e] + si * tg;
            float hv = so * tanh_fast(cn);
            creg[e] = cn;
            Ht[(w * 16 + q * 4 + gp * 2 + e) * 8 + hcl] = f2bf(hv);
            if (glast) {
                hT[b * HID + hc0 + hcl] = hv;
                cT[b * HID + hc0 + hcl] = cn;
            }
        }
        xw[0] = xwn[0]; xw[1] = xwn[1];
        __syncthreads();   // Ht complete

        // ---- packed h stores: 64 x 16B CONTIGUOUS (8 full lines, single writer) ----
        short* hn = hist + (size_t)(tt + 1) * BATCH * HID
                  + (size_t)cg * (BATCH * 8) + (size_t)bb * 8;
        if (tid < 64)
            store16_wt(&hn[tid * 8], *(const i4*)&Ht[tid * 8]);

        // ---- aggregator barrier (r7 topology, lowest congestion) ----
        if (tt < TC - 1) {
            __syncthreads();   // drains vmcnt for the 64 storing threads
            const int base = (tt * 4 + bg) * 128 * FPAD;
            if (tid == 0)
                __hip_atomic_store(&flags[base + cg * FPAD], 1,
                                   __ATOMIC_RELAXED, __HIP_MEMORY_SCOPE_AGENT);
            if (cg == 0) {
                if (tid < 128) {
                    while (__hip_atomic_load(&flags[base + tid * FPAD],
                                             __ATOMIC_RELAXED, __HIP_MEMORY_SCOPE_AGENT) == 0)
                        __builtin_amdgcn_s_sleep(1);
                }
                __syncthreads();
                if (tid == 0)
                    __hip_atomic_store(&go[(tt * 4 + bg) * FPAD], 1,
                                       __ATOMIC_RELAXED, __HIP_MEMORY_SCOPE_AGENT);
            } else {
                if (tid == 0) {
                    while (__hip_atomic_load(&go[(tt * 4 + bg) * FPAD],
                                             __ATOMIC_RELAXED, __HIP_MEMORY_SCOPE_AGENT) == 0)
                        __builtin_amdgcn_s_sleep(1);
                }
                __syncthreads();
            }
        }
    }

#undef ISSUE_A
#undef COMPUTE_A

    // ---- write back c-state for next chunk ----
#pragma unroll
    for (int e = 0; e < 2; ++e)
        cf[(size_t)(rowb + e) * HID + hc0 + hcl] = creg[e];
}

// ---------------- output head over the FULL h history (blocked layout) ----------------
__global__ __launch_bounds__(256) void out_head(const short* __restrict__ hs,
                                                const float* __restrict__ Wout,
                                                const float* __restrict__ bout,
                                                float* __restrict__ out) {
    int row = blockIdx.x * 4 + (threadIdx.x >> 6);   // tt*256 + b
    int lane = threadIdx.x & 63;
    int tt = row >> 8, b = row & 255;
    const short* sb = hs + (size_t)(tt + 1) * BATCH * HID + b * 8;   // slot tt+1
    const float2* w2 = (const float2*)Wout;
    float s = 0.f;
#pragma unroll
    for (int j = 0; j < 8; ++j) {
        int m = j * 64 + lane;                       // pair index 0..511, k=2m
        int pk = *(const int*)&sb[(size_t)(m >> 2) * (BATCH * 8) + 2 * (m & 3)];
        float2 wv = w2[m];
        union { unsigned u; float f; } lo, hi;
        lo.u = ((unsigned)pk) << 16;
        hi.u = ((unsigned)pk) & 0xffff0000u;
        s += lo.f * wv.x + hi.f * wv.y;
    }
#pragma unroll
    for (int off = 32; off; off >>= 1) s += __shfl_down(s, off);
    if (lane == 0) out[row] = s + bout[0];
}

// ---------------------------------------------------------------------------
extern "C" void kernel_launch(void* const* d_in, const int* in_sizes, int n_in,
                              void* d_out, int out_size, void* d_ws, size_t ws_size,
                              hipStream_t stream) {
    const float* inputs = (const float*)d_in[0];
    const float* h0     = (const float*)d_in[1];
    const float* c0     = (const float*)d_in[2];
    const float* W1     = (const float*)d_in[3];
    const float* b1     = (const float*)d_in[4];
    const float* W_ih   = (const float*)d_in[5];
    const float* W_hh   = (const float*)d_in[6];
    const float* b_ih   = (const float*)d_in[7];
    const float* b_hh   = (const float*)d_in[8];
    const float* W_out  = (const float*)d_in[9];
    const float* b_out  = (const float*)d_in[10];

    float* out = (float*)d_out;
    float* hT  = out + (size_t)T_STEPS * BATCH;
    float* cT  = hT + (size_t)BATCH * HID;

    char* base = (char*)d_ws;
    size_t off = 0;
    auto alloc = [&](size_t bytes) -> char* {
        char* q = base + off;
        off += (bytes + 255) & ~(size_t)255;
        return q;
    };
    short* W1b   = (short*)alloc((size_t)HID * DIM * 2);
    short* Wihb  = (short*)alloc((size_t)GATES * HID * 2);      // row-permuted
    short* Whhb  = (short*)alloc((size_t)GATES * HID * 2);      // plain layout
    float* biasf = (float*)alloc((size_t)GATES * 4);            // permuted
    float* cf    = (float*)alloc((size_t)BATCH * HID * 4);
    int*   flags = (int*)alloc((size_t)T_STEPS * 4 * 128 * FPAD * 4);  // 8 MB
    int*   go    = (int*)alloc((size_t)T_STEPS * 4 * FPAD * 4);        // 64 KB

    short* xb_a  = (short*)alloc((size_t)T_STEPS * BATCH * HID * 2);   // 67 MB
    short* hhist = (short*)alloc((size_t)(T_STEPS + 1) * BATCH * HID * 2); // 64.5 MB

    // ---- ws-adaptive xg path ----
    // all-path: one region holds inb_a early (dead after gemm1), xgb_all later.
    size_t xg_all_bytes = (size_t)T_STEPS * BATCH * GATES * 2;          // 268 MB
    size_t inb_bytes    = (size_t)T_STEPS * BATCH * DIM * 2;            // 33.5 MB
    int ALLX = (ws_size - off) >= (xg_all_bytes + 4096);
    short *xgb = nullptr, *inb_a = nullptr;
    int TC = 32;
    if (ALLX) {
        xgb   = (short*)alloc(xg_all_bytes);
        inb_a = xgb;                             // aliased; dead before xgb written
    } else {
        size_t per_c = (size_t)TC * BATCH * GATES * 2;
        while (TC > 1 && off + (per_c > inb_bytes ? per_c : inb_bytes) + 4096 > ws_size) {
            TC >>= 1;
            per_c = (size_t)TC * BATCH * GATES * 2;
        }
        size_t region = per_c > inb_bytes ? per_c : inb_bytes;
        xgb   = (short*)alloc(region);
        inb_a = xgb;                             // aliased; dead before xgb written
    }

    // ---- weight prep + flag zero (flags indexed by absolute t -> zero once) ----
    cvt_f32_bf16<<<(HID * DIM / 4 + 255) / 256, 256, 0, stream>>>(W1, W1b, HID * DIM / 4);
    cvt_permute_rows<<<GATES, 256, 0, stream>>>(W_ih, Wihb);
    cvt_f32_bf16<<<(GATES * HID / 4 + 255) / 256, 256, 0, stream>>>(W_hh, Whhb, GATES * HID / 4);
    bias_sum_perm<<<GATES / 256, 256, 0, stream>>>(b_ih, b_hh, biasf);
    cvt_h0_blocked<<<BATCH, 256, 0, stream>>>(h0, hhist);
    copy_f32v4<<<(BATCH * HID / 4 + 255) / 256, 256, 0, stream>>>(c0, cf, BATCH * HID / 4);
    zero_i32<<<512, 256, 0, stream>>>(flags, T_STEPS * 4 * 128 * FPAD + T_STEPS * 4 * FPAD);

    // ---- upfront: convert ALL inputs, first-layer GEMM for ALL timesteps ----
    {
        int Ma = T_STEPS * BATCH;                       // 32768
        cvt_f32_bf16<<<(Ma * DIM / 4 + 255) / 256, 256, 0, stream>>>(
            inputs, inb_a, Ma * DIM / 4);
        gemm_bt2<<<dim3(Ma / 128, HID / 128), 256, 0, stream>>>(
            inb_a, W1b, b1, xb_a, Ma, HID, DIM, 1);     // grid 256x8 = 2048
        if (ALLX) {
            // ALL xg in one dispatch (measurable in top-5)
            gemm_bt2<<<dim3(Ma / 128, GATES / 128), 256, 0, stream>>>(
                xb_a, Wihb, biasf, xgb, Ma, GATES, HID, 0);   // grid 256x32 = 8192
        }
    }

    // ---- chunked recurrence over in-place h history ----
    for (int t0 = 0; t0 < T_STEPS; t0 += TC) {
        int last = (t0 + TC >= T_STEPS);
        const short* xgc;
        if (ALLX) {
            xgc = xgb + (size_t)t0 * BATCH * GATES;
        } else {
            int Mc = TC * BATCH;
            gemm_bt2<<<dim3(Mc / 128, GATES / 128), 256, 0, stream>>>(
                xb_a + (size_t)t0 * BATCH * HID, Wihb, biasf, xgb,
                Mc, GATES, HID, 0);
            xgc = xgb;
        }

        lstm_persist<<<512, 256, 0, stream>>>(Whhb, xgc,
                                              hhist + (size_t)t0 * BATCH * HID,
                                              cf, hT, cT,
                                              flags + (size_t)t0 * 4 * 128 * FPAD,
                                              go + (size_t)t0 * 4 * FPAD,
                                              TC, last);
    }

    // ---- output head once over the full history ----
    out_head<<<T_STEPS * BATCH / 4, 256, 0, stream>>>(hhist, W_out, b_out, out);
}

// Round 10
// 1166.234 us; speedup vs baseline: 1.1467x; 1.0943x over previous
//
#include <hip/hip_runtime.h>
#include <hip/hip_bf16.h>
#include <math.h>

// ---------------------------------------------------------------------------
// LSTM_55327768708454:  T=128 B=256 D=512 H=1024 O=1
// Round 19: gemm_bt8 = 256^2 tile / BK=64 / 8-wave / 8-phase counted-vmcnt
//   schedule (T3+T4). Per phase: barrier -> ds-read subtile -> 1 half-tile
//   stage (2 gll16) -> 16 MFMA. vmcnt(4) at phases 0/4 only (vmcnt(0) at p4
//   of the last iteration: tail-guarded stages shrink the in-flight ledger).
//   Stage schedule (verified freed-before-issue + landed-before-use):
//     p0,p1: A(kt1) | p2,p3: B(kt0+2) | p4,p5: A(kt0+2) | p6,p7: B(kt1+2)
//   Prologue: A(0),B(0),B(1). LDS 128 KB, swizzle slot^=(row&7) (bt2-verified).
//   persist = EXACT r11 (frozen); harness = r18 (hist_all, ws-adaptive xg).
// ---------------------------------------------------------------------------

#define T_STEPS 128
#define BATCH   256
#define DIM     512
#define HID     1024
#define GATES   4096
#define FPAD    32   // ints per flag slot (128B)

typedef __attribute__((ext_vector_type(8))) short short8;
typedef __attribute__((ext_vector_type(4))) float f4;
typedef __attribute__((ext_vector_type(4))) int i4;

__device__ __forceinline__ short f2bf(float f) {
    union { float f; unsigned u; } x; x.f = f;
    unsigned r = (x.u + 0x7fffu + ((x.u >> 16) & 1u)) >> 16;
    return (short)r;
}
__device__ __forceinline__ float bf2f(short s) {
    union { unsigned u; float f; } x; x.u = ((unsigned)(unsigned short)s) << 16;
    return x.f;
}
__device__ __forceinline__ float sigm(float x) { return 1.f / (1.f + __expf(-x)); }
__device__ __forceinline__ float tanh_fast(float x) { return 2.f / (1.f + __expf(-2.f * x)) - 1.f; }

__device__ __forceinline__ void gll16(const void* g, void* l) {
    __builtin_amdgcn_global_load_lds(
        (const __attribute__((address_space(1))) void*)g,
        (__attribute__((address_space(3))) void*)l, 16, 0, 0);
}
__device__ __forceinline__ void store16_wt(void* p, i4 v) {
    asm volatile("global_store_dwordx4 %0, %1, off sc0 sc1"
                 :: "v"(p), "v"(v) : "memory");
}

// ---------------- helpers ----------------
__global__ __launch_bounds__(256) void cvt_f32_bf16(const float* __restrict__ in,
                                                    short* __restrict__ out, int n4) {
    int i = blockIdx.x * 256 + threadIdx.x;
    if (i < n4) {
        float4 v = ((const float4*)in)[i];
        union { short s[4]; long long ll; } r;
        r.s[0] = f2bf(v.x); r.s[1] = f2bf(v.y); r.s[2] = f2bf(v.z); r.s[3] = f2bf(v.w);
        ((long long*)out)[i] = r.ll;
    }
}

// h0 fp32 (B,H) -> blocked bf16 [slice][b][8]
__global__ __launch_bounds__(256) void cvt_h0_blocked(const float* __restrict__ h0,
                                                      short* __restrict__ dst) {
    int b = blockIdx.x, k0 = threadIdx.x * 4;
    float4 v = *(const float4*)&h0[(size_t)b * HID + k0];
    union { short s[4]; long long ll; } p;
    p.s[0] = f2bf(v.x); p.s[1] = f2bf(v.y); p.s[2] = f2bf(v.z); p.s[3] = f2bf(v.w);
    *(long long*)&dst[(k0 >> 3) * (BATCH * 8) + b * 8 + (k0 & 7)] = p.ll;
}

// out row r' = hc*4+g  <-  in row g*1024+hc  (W_ih: xg cols gate-packed)
__global__ __launch_bounds__(256) void cvt_permute_rows(const float* __restrict__ in,
                                                        short* __restrict__ out) {
    int r = blockIdx.x;
    int hc = r >> 2, g = r & 3;
    const float* src = in + (size_t)(g * HID + hc) * HID;
    short* dst = out + (size_t)r * HID;
    int c = threadIdx.x * 4;
    float4 v = *(const float4*)&src[c];
    union { short s[4]; long long ll; } p;
    p.s[0] = f2bf(v.x); p.s[1] = f2bf(v.y); p.s[2] = f2bf(v.z); p.s[3] = f2bf(v.w);
    *(long long*)&dst[c] = p.ll;
}

__global__ __launch_bounds__(256) void bias_sum_perm(const float* __restrict__ a,
                                                     const float* __restrict__ b,
                                                     float* __restrict__ o) {
    int r = blockIdx.x * 256 + threadIdx.x;
    int hc = r >> 2, g = r & 3;
    int src = g * HID + hc;
    o[r] = a[src] + b[src];
}

__global__ __launch_bounds__(256) void copy_f32v4(const float* __restrict__ in,
                                                  float* __restrict__ out, int n4) {
    int i = blockIdx.x * 256 + threadIdx.x;
    if (i < n4) ((float4*)out)[i] = ((const float4*)in)[i];
}

__global__ __launch_bounds__(256) void zero_i32(int* __restrict__ p, int n) {
    for (int i = blockIdx.x * 256 + threadIdx.x; i < n; i += gridDim.x * 256)
        p[i] = 0;
}

// ---------------- gemm_bt8: 256^2 / BK=64 / 8-wave / 8-phase counted vmcnt ---
// C = A @ B^T + bias, opt relu. A:(M,K) B:(N,K) row-major bf16, C bf16.
// Requires M%256==0, N%256==0, K%128==0, grid (M/256, N/256), 512 threads.
// LDS: As/Bs[kt&1][256][64]; 16B slot s of row r holds global slot s^(r&7).
__global__ __launch_bounds__(512) void gemm_bt8(const short* __restrict__ A,
                                                const short* __restrict__ B,
                                                const float* __restrict__ bias,
                                                short* __restrict__ C,
                                                int M, int N, int K, int do_relu) {
    __shared__ __align__(16) short As[2][256 * 64];   // 64 KB
    __shared__ __align__(16) short Bs[2][256 * 64];   // 64 KB
    const int tid = threadIdx.x, w = tid >> 6, lane = tid & 63;
    const int wr = w >> 2, wc = w & 3;                // wave tile: 128 x 64

    // XCD-aware bijective block swizzle (m204 form)
    const int nwg = gridDim.x * gridDim.y;
    const int flat = blockIdx.y * gridDim.x + blockIdx.x;
    const int qq = nwg >> 3, rr = nwg & 7;
    const int xcd = flat & 7, oin = flat >> 3;
    const int swz = (xcd < rr ? xcd * (qq + 1) : rr * (qq + 1) + (xcd - rr) * qq) + oin;
    const int bm = (swz % gridDim.x) * 256, bn = (swz / gridDim.x) * 256;

    const int NT = K >> 6, NI = NT >> 1;

    // one half-tile = 128 rows = 2 gll16 issues (each: 8 rows/wave x 8 waves)
#define STG(P, L, bmn, kt, h)                                                  \
    if ((kt) < NT) {                                                           \
        _Pragma("unroll")                                                      \
        for (int s_ = 0; s_ < 2; ++s_) {                                       \
            int r0_ = (h) * 128 + s_ * 64 + w * 8;                             \
            int row_ = r0_ + (lane >> 3);                                      \
            int kof_ = ((lane & 7) ^ (row_ & 7)) * 8;                          \
            gll16(&P[(size_t)((bmn) + row_) * K + (kt) * 64 + kof_],           \
                  &L[(kt) & 1][r0_ * 64]);                                     \
        }                                                                      \
    }

#define LOADB(kt)                                                              \
    _Pragma("unroll")                                                          \
    for (int nf = 0; nf < 4; ++nf)                                             \
        _Pragma("unroll")                                                      \
        for (int ks = 0; ks < 2; ++ks) {                                       \
            int rb_ = wc * 64 + nf * 16 + (lane & 15);                         \
            int sb_ = (ks * 4 + (lane >> 4)) ^ (rb_ & 7);                      \
            bfr[nf][ks] = *(const short8*)&Bs[(kt) & 1][rb_ * 64 + sb_ * 8];   \
        }

#define LOADA(kt, q)                                                           \
    _Pragma("unroll")                                                          \
    for (int mi = 0; mi < 2; ++mi)                                             \
        _Pragma("unroll")                                                      \
        for (int ks = 0; ks < 2; ++ks) {                                       \
            int ra_ = wr * 128 + ((q) * 2 + mi) * 16 + (lane & 15);            \
            int sa_ = (ks * 4 + (lane >> 4)) ^ (ra_ & 7);                      \
            af[mi][ks] = *(const short8*)&As[(kt) & 1][ra_ * 64 + sa_ * 8];    \
        }

#define MFMAQ(q)                                                               \
    __builtin_amdgcn_s_setprio(1);                                             \
    _Pragma("unroll")                                                          \
    for (int mi = 0; mi < 2; ++mi)                                             \
        _Pragma("unroll")                                                      \
        for (int nf = 0; nf < 4; ++nf)                                         \
            _Pragma("unroll")                                                  \
            for (int ks = 0; ks < 2; ++ks)                                     \
                acc[(q) * 2 + mi][nf] = __builtin_amdgcn_mfma_f32_16x16x32_bf16( \
                    af[mi][ks], bfr[nf][ks], acc[(q) * 2 + mi][nf], 0, 0, 0);  \
    __builtin_amdgcn_s_setprio(0);                                             \
    __builtin_amdgcn_sched_barrier(0);

#define VM4 asm volatile("s_waitcnt vmcnt(4)" ::: "memory");
#define VM0 asm volatile("s_waitcnt vmcnt(0)" ::: "memory");
#define BAR __builtin_amdgcn_s_barrier();

    f4 acc[8][4] = {};

    // prologue: A(0) h0,h1; B(0) h0,h1; B(1) h0,h1  (12 gloads/wave in flight)
    STG(A, As, bm, 0, 0) STG(A, As, bm, 0, 1)
    STG(B, Bs, bn, 0, 0) STG(B, Bs, bn, 0, 1)
    STG(B, Bs, bn, 1, 0) STG(B, Bs, bn, 1, 1)

    for (int it = 0; it < NI; ++it) {
        const int kt0 = 2 * it, kt1 = 2 * it + 1;
        const int lastit = (it + 1 == NI);
        short8 bfr[4][2], af[2][2];

        // ---- K-tile kt0: phases 0..3 ----
        VM4 BAR                      // A(kt0),B(kt0) landed (8 oldest drained)
        LOADB(kt0) LOADA(kt0, 0)
        STG(A, As, bm, kt1, 0)       // buf1 A freed after prev p7
        MFMAQ(0)
        BAR
        LOADA(kt0, 1)
        STG(A, As, bm, kt1, 1)
        MFMAQ(1)
        BAR
        LOADA(kt0, 2)
        STG(B, Bs, bn, kt0 + 2, 0)   // buf0 B freed after p0
        MFMAQ(2)
        BAR
        LOADA(kt0, 3)
        STG(B, Bs, bn, kt0 + 2, 1)
        MFMAQ(3)

        // ---- K-tile kt1: phases 4..7 ----
        if (lastit) { VM0 } else { VM4 }   // A(kt1),B(kt1) landed
        BAR
        LOADB(kt1) LOADA(kt1, 0)
        STG(A, As, bm, kt0 + 2, 0)   // buf0 A freed after p3
        MFMAQ(0)
        BAR
        LOADA(kt1, 1)
        STG(A, As, bm, kt0 + 2, 1)
        MFMAQ(1)
        BAR
        LOADA(kt1, 2)
        STG(B, Bs, bn, kt1 + 2, 0)   // buf1 B freed after p4
        MFMAQ(2)
        BAR
        LOADA(kt1, 3)
        STG(B, Bs, bn, kt1 + 2, 1)
        MFMAQ(3)
    }
#undef STG
#undef LOADB
#undef LOADA
#undef MFMAQ
#undef VM4
#undef VM0
#undef BAR

    // ---- epilogue: C = acc + bias (opt relu) ----
    const int lc = lane & 15, lr = (lane >> 4) * 4;
#pragma unroll
    for (int mf = 0; mf < 8; ++mf) {
#pragma unroll
        for (int nf = 0; nf < 4; ++nf) {
            int col = bn + wc * 64 + nf * 16 + lc;
            float bv = bias[col];
#pragma unroll
            for (int r = 0; r < 4; ++r) {
                int row = bm + wr * 128 + mf * 16 + lr + r;
                float v = acc[mf][nf][r] + bv;
                if (do_relu) v = fmaxf(v, 0.f);
                C[(size_t)row * N + col] = f2bf(v);
            }
        }
    }
}

// ---------------- persistent recurrence over TC steps (EXACT r11) ----------------
// 512 blocks (2/CU): bg = bx>>7 (64 batch rows), cg = bx&127 (8 h-cols).
// hist slots are BLOCKED: [slice(=k/8)][b][8], slice cg owned by block (.,cg).
// K-loop: A-loads pipelined 3 groups deep; MFMA clusters in s_setprio.
// Aggregator barrier (r7 topology).
__global__ __launch_bounds__(256) void lstm_persist(const short* __restrict__ Whh,
                                                    const short* __restrict__ xgc,
                                                    short* __restrict__ hist,
                                                    float* __restrict__ cf,
                                                    float* __restrict__ hT,
                                                    float* __restrict__ cT,
                                                    int* __restrict__ flags,
                                                    int* __restrict__ go,
                                                    int TC, int last) {
    __shared__ __align__(16) short Bf[32768];   // 64 KB W_hh strip fragments
    __shared__ __align__(16) short Ht[512];     // 1 KB h-tile staging (64 rows x 8 cols)
    const int tid = threadIdx.x, w = tid >> 6, lane = tid & 63;
    const int bg = blockIdx.x >> 7, cg = blockIdx.x & 127;
    const int bb = bg * 64, hc0 = cg * 8;
    const int hcl = lane & 7, gp = (lane >> 3) & 1, q = lane >> 4;

    // ---- fill W_hh strip fragments once ----
#pragma unroll
    for (int i = 0; i < 16; ++i) {
        int p = w * 16 + i;
        int c = p >> 1, t = p & 1;
        gll16(&Whh[(size_t)((t * 2 + gp) * HID + hc0 + hcl) * HID + c * 32 + q * 8],
              &Bf[p * 512]);
    }

    // ---- c-state into registers ----
    const int rowb = bb + w * 16 + q * 4 + gp * 2;       // rows rowb, rowb+1
    float creg[2];
#pragma unroll
    for (int e = 0; e < 2; ++e)
        creg[e] = cf[(size_t)(rowb + e) * HID + hc0 + hcl];

    __syncthreads();   // strip ready

    // prime xg for step 0
    unsigned long long xw[2], xwn[2];
#pragma unroll
    for (int e = 0; e < 2; ++e)
        xw[e] = *(const unsigned long long*)&xgc[(size_t)(rowb + e) * GATES
                                                 + (hc0 + hcl) * 4];

#define ISSUE_A(buf, g)                                                        \
    _Pragma("unroll")                                                          \
    for (int i = 0; i < 8; ++i)                                                \
        buf[i] = *(const short8*)(abase + (size_t)((g) * 8 + i) * astr);

#define COMPUTE_A(buf, g)                                                      \
    __builtin_amdgcn_s_setprio(1);                                             \
    _Pragma("unroll")                                                          \
    for (int i = 0; i < 8; ++i) {                                              \
        short8 b0 = *(const short8*)&Bf[(((g) * 8 + i) * 2 + 0) * 512 + lane * 8]; \
        short8 b1 = *(const short8*)&Bf[(((g) * 8 + i) * 2 + 1) * 512 + lane * 8]; \
        acc0 = __builtin_amdgcn_mfma_f32_16x16x32_bf16(buf[i], b0, acc0, 0, 0, 0); \
        acc1 = __builtin_amdgcn_mfma_f32_16x16x32_bf16(buf[i], b1, acc1, 0, 0, 0); \
    }                                                                          \
    __builtin_amdgcn_s_setprio(0);

    for (int tt = 0; tt < TC; ++tt) {
        // ---- prefetch next step's xg ----
        if (tt + 1 < TC) {
#pragma unroll
            for (int e = 0; e < 2; ++e)
                xwn[e] = *(const unsigned long long*)&xgc[(size_t)((tt + 1) * BATCH + rowb + e) * GATES
                                                          + (hc0 + hcl) * 4];
        }

        // ---- K-loop: A from blocked hist (slice = c*4+q), B resident in LDS,
        //      3-group-deep explicit A prefetch pipeline ----
        const short* abase = hist + (size_t)tt * BATCH * HID
                           + (size_t)q * (BATCH * 8) + (size_t)(bb + w * 16 + (lane & 15)) * 8;
        const size_t astr = (size_t)4 * (BATCH * 8);
        f4 acc0 = {}, acc1 = {};
        short8 ab0[8], ab1[8], ab2[8];
        ISSUE_A(ab0, 0)
        ISSUE_A(ab1, 1)
        ISSUE_A(ab2, 2)
        COMPUTE_A(ab0, 0)
        ISSUE_A(ab0, 3)
        COMPUTE_A(ab1, 1)
        COMPUTE_A(ab2, 2)
        COMPUTE_A(ab0, 3)

        // ---- gate exchange across lane^8 ----
        float p0[4], p1[4];
#pragma unroll
        for (int r = 0; r < 4; ++r) {
            p0[r] = __shfl_xor(acc0[r], 8);
            p1[r] = __shfl_xor(acc1[r], 8);
        }

        int glast = last && (tt == TC - 1);
#pragma unroll
        for (int e = 0; e < 2; ++e) {
            int r = gp * 2 + e;
            size_t b = rowb + e;
            float gi = gp ? p0[r] : acc0[r];
            float gf = gp ? acc0[r] : p0[r];
            float gg = gp ? p1[r] : acc1[r];
            float go_ = gp ? acc1[r] : p1[r];
            gi += bf2f((short)(xw[e] & 0xffff));
            gf += bf2f((short)((xw[e] >> 16) & 0xffff));
            gg += bf2f((short)((xw[e] >> 32) & 0xffff));
            go_ += bf2f((short)((xw[e] >> 48) & 0xffff));
            float si = sigm(gi), sf = sigm(gf), tg = tanh_fast(gg), so = sigm(go_);
            float cn = sf * creg[e] + si * tg;
            float hv = so * tanh_fast(cn);
            creg[e] = cn;
            Ht[(w * 16 + q * 4 + gp * 2 + e) * 8 + hcl] = f2bf(hv);
            if (glast) {
                hT[b * HID + hc0 + hcl] = hv;
                cT[b * HID + hc0 + hcl] = cn;
            }
        }
        xw[0] = xwn[0]; xw[1] = xwn[1];
        __syncthreads();   // Ht complete

        // ---- packed h stores: 64 x 16B CONTIGUOUS (8 full lines, single writer) ----
        short* hn = hist + (size_t)(tt + 1) * BATCH * HID
                  + (size_t)cg * (BATCH * 8) + (size_t)bb * 8;
        if (tid < 64)
            store16_wt(&hn[tid * 8], *(const i4*)&Ht[tid * 8]);

        // ---- aggregator barrier (r7 topology, lowest congestion) ----
        if (tt < TC - 1) {
            __syncthreads();   // drains vmcnt for the 64 storing threads
            const int base = (tt * 4 + bg) * 128 * FPAD;
            if (tid == 0)
                __hip_atomic_store(&flags[base + cg * FPAD], 1,
                                   __ATOMIC_RELAXED, __HIP_MEMORY_SCOPE_AGENT);
            if (cg == 0) {
                if (tid < 128) {
                    while (__hip_atomic_load(&flags[base + tid * FPAD],
                                             __ATOMIC_RELAXED, __HIP_MEMORY_SCOPE_AGENT) == 0)
                        __builtin_amdgcn_s_sleep(1);
                }
                __syncthreads();
                if (tid == 0)
                    __hip_atomic_store(&go[(tt * 4 + bg) * FPAD], 1,
                                       __ATOMIC_RELAXED, __HIP_MEMORY_SCOPE_AGENT);
            } else {
                if (tid == 0) {
                    while (__hip_atomic_load(&go[(tt * 4 + bg) * FPAD],
                                             __ATOMIC_RELAXED, __HIP_MEMORY_SCOPE_AGENT) == 0)
                        __builtin_amdgcn_s_sleep(1);
                }
                __syncthreads();
            }
        }
    }

#undef ISSUE_A
#undef COMPUTE_A

    // ---- write back c-state for next chunk ----
#pragma unroll
    for (int e = 0; e < 2; ++e)
        cf[(size_t)(rowb + e) * HID + hc0 + hcl] = creg[e];
}

// ---------------- output head over the FULL h history (blocked layout) ----------------
__global__ __launch_bounds__(256) void out_head(const short* __restrict__ hs,
                                                const float* __restrict__ Wout,
                                                const float* __restrict__ bout,
                                                float* __restrict__ out) {
    int row = blockIdx.x * 4 + (threadIdx.x >> 6);   // tt*256 + b
    int lane = threadIdx.x & 63;
    int tt = row >> 8, b = row & 255;
    const short* sb = hs + (size_t)(tt + 1) * BATCH * HID + b * 8;   // slot tt+1
    const float2* w2 = (const float2*)Wout;
    float s = 0.f;
#pragma unroll
    for (int j = 0; j < 8; ++j) {
        int m = j * 64 + lane;                       // pair index 0..511, k=2m
        int pk = *(const int*)&sb[(size_t)(m >> 2) * (BATCH * 8) + 2 * (m & 3)];
        float2 wv = w2[m];
        union { unsigned u; float f; } lo, hi;
        lo.u = ((unsigned)pk) << 16;
        hi.u = ((unsigned)pk) & 0xffff0000u;
        s += lo.f * wv.x + hi.f * wv.y;
    }
#pragma unroll
    for (int off = 32; off; off >>= 1) s += __shfl_down(s, off);
    if (lane == 0) out[row] = s + bout[0];
}

// ---------------------------------------------------------------------------
extern "C" void kernel_launch(void* const* d_in, const int* in_sizes, int n_in,
                              void* d_out, int out_size, void* d_ws, size_t ws_size,
                              hipStream_t stream) {
    const float* inputs = (const float*)d_in[0];
    const float* h0     = (const float*)d_in[1];
    const float* c0     = (const float*)d_in[2];
    const float* W1     = (const float*)d_in[3];
    const float* b1     = (const float*)d_in[4];
    const float* W_ih   = (const float*)d_in[5];
    const float* W_hh   = (const float*)d_in[6];
    const float* b_ih   = (const float*)d_in[7];
    const float* b_hh   = (const float*)d_in[8];
    const float* W_out  = (const float*)d_in[9];
    const float* b_out  = (const float*)d_in[10];

    float* out = (float*)d_out;
    float* hT  = out + (size_t)T_STEPS * BATCH;
    float* cT  = hT + (size_t)BATCH * HID;

    char* base = (char*)d_ws;
    size_t off = 0;
    auto alloc = [&](size_t bytes) -> char* {
        char* q = base + off;
        off += (bytes + 255) & ~(size_t)255;
        return q;
    };
    short* W1b   = (short*)alloc((size_t)HID * DIM * 2);
    short* Wihb  = (short*)alloc((size_t)GATES * HID * 2);      // row-permuted
    short* Whhb  = (short*)alloc((size_t)GATES * HID * 2);      // plain layout
    float* biasf = (float*)alloc((size_t)GATES * 4);            // permuted
    float* cf    = (float*)alloc((size_t)BATCH * HID * 4);
    int*   flags = (int*)alloc((size_t)T_STEPS * 4 * 128 * FPAD * 4);  // 8 MB
    int*   go    = (int*)alloc((size_t)T_STEPS * 4 * FPAD * 4);        // 64 KB

    short* xb_a  = (short*)alloc((size_t)T_STEPS * BATCH * HID * 2);   // 67 MB
    short* hhist = (short*)alloc((size_t)(T_STEPS + 1) * BATCH * HID * 2); // 64.5 MB

    // ---- ws-adaptive xg path ----
    size_t xg_all_bytes = (size_t)T_STEPS * BATCH * GATES * 2;          // 268 MB
    size_t inb_bytes    = (size_t)T_STEPS * BATCH * DIM * 2;            // 33.5 MB
    int ALLX = (ws_size - off) >= (xg_all_bytes + 4096);
    short *xgb = nullptr, *inb_a = nullptr;
    int TC = 32;
    if (ALLX) {
        xgb   = (short*)alloc(xg_all_bytes);
        inb_a = xgb;                             // aliased; dead before xgb written
    } else {
        size_t per_c = (size_t)TC * BATCH * GATES * 2;
        while (TC > 1 && off + (per_c > inb_bytes ? per_c : inb_bytes) + 4096 > ws_size) {
            TC >>= 1;
            per_c = (size_t)TC * BATCH * GATES * 2;
        }
        size_t region = per_c > inb_bytes ? per_c : inb_bytes;
        xgb   = (short*)alloc(region);
        inb_a = xgb;                             // aliased; dead before xgb written
    }

    // ---- weight prep + flag zero (flags indexed by absolute t -> zero once) ----
    cvt_f32_bf16<<<(HID * DIM / 4 + 255) / 256, 256, 0, stream>>>(W1, W1b, HID * DIM / 4);
    cvt_permute_rows<<<GATES, 256, 0, stream>>>(W_ih, Wihb);
    cvt_f32_bf16<<<(GATES * HID / 4 + 255) / 256, 256, 0, stream>>>(W_hh, Whhb, GATES * HID / 4);
    bias_sum_perm<<<GATES / 256, 256, 0, stream>>>(b_ih, b_hh, biasf);
    cvt_h0_blocked<<<BATCH, 256, 0, stream>>>(h0, hhist);
    copy_f32v4<<<(BATCH * HID / 4 + 255) / 256, 256, 0, stream>>>(c0, cf, BATCH * HID / 4);
    zero_i32<<<512, 256, 0, stream>>>(flags, T_STEPS * 4 * 128 * FPAD + T_STEPS * 4 * FPAD);

    // ---- upfront: convert ALL inputs, first-layer GEMM for ALL timesteps ----
    {
        int Ma = T_STEPS * BATCH;                       // 32768
        cvt_f32_bf16<<<(Ma * DIM / 4 + 255) / 256, 256, 0, stream>>>(
            inputs, inb_a, Ma * DIM / 4);
        gemm_bt8<<<dim3(Ma / 256, HID / 256), 512, 0, stream>>>(
            inb_a, W1b, b1, xb_a, Ma, HID, DIM, 1);     // grid 128x4 = 512
        if (ALLX) {
            gemm_bt8<<<dim3(Ma / 256, GATES / 256), 512, 0, stream>>>(
                xb_a, Wihb, biasf, xgb, Ma, GATES, HID, 0);   // grid 128x16
        }
    }

    // ---- chunked recurrence over in-place h history ----
    for (int t0 = 0; t0 < T_STEPS; t0 += TC) {
        int last = (t0 + TC >= T_STEPS);
        const short* xgc;
        if (ALLX) {
            xgc = xgb + (size_t)t0 * BATCH * GATES;
        } else {
            int Mc = TC * BATCH;
            gemm_bt8<<<dim3(Mc / 256, GATES / 256), 512, 0, stream>>>(
                xb_a + (size_t)t0 * BATCH * HID, Wihb, biasf, xgb,
                Mc, GATES, HID, 0);                      // grid 32x16 = 512
            xgc = xgb;
        }

        lstm_persist<<<512, 256, 0, stream>>>(Whhb, xgc,
                                              hhist + (size_t)t0 * BATCH * HID,
                                              cf, hT, cT,
                                              flags + (size_t)t0 * 4 * 128 * FPAD,
                                              go + (size_t)t0 * 4 * FPAD,
                                              TC, last);
    }

    // ---- output head once over the full history ----
    out_head<<<T_STEPS * BATCH / 4, 256, 0, stream>>>(hhist, W_out, b_out, out);
}